// Round 16
// baseline (225.375 us; speedup 1.0000x reference)
//
#include <hip/hip_runtime.h>
#include <hip/hip_bf16.h>

#define KK 5
constexpr int N0 = 78400;     // B*28*28
constexpr int E0 = 627200;    // N0*8
constexpr int N1 = 19600;     // B*14*14
constexpr int E1 = 156800;    // N1*8
constexpr int C1 = 32, C2 = 64;
constexpr int BSZ = 100;
constexpr int FC1_IN = 3136, FC1_OUT = 512;
constexpr int NKEYS = 98000;  // N0 + N1 global node keys
constexpr int NCOARSE = 383;  // coarse buckets of 256 keys
constexpr int CAPB = 2400;    // bucket capacity: Poisson(2048) + 7.7 sigma
constexpr int KEXT = 832;     // 800 tap-space + 32 root channels
constexpr int ULS = 836;      // LDS fp32 U row stride
constexpr int UBS = 856;      // LDS bf16 U row stride (ushorts): 16B-aligned rows, 12-bank stagger
constexpr int CH2 = 160;      // conv2 edge staging chunk (block avg ~64)

typedef __attribute__((ext_vector_type(8))) short bf16x8;
typedef __attribute__((ext_vector_type(4))) float f32x4;

__device__ __forceinline__ unsigned short f2bf(float f) {
    union { float f; unsigned u; } v; v.f = f;
    unsigned u = v.u;
    unsigned r = (u + 0x7FFF + ((u >> 16) & 1)) >> 16;   // RNE
    return (unsigned short)r;
}

__device__ __forceinline__ void taps4(float px, float py,
                                      int& a00, int& a01, int& a10, int& a11,
                                      float& fx, float& fy) {
    float kfx = floorf(px), kfy = floorf(py);
    fx = px - kfx; fy = py - kfy;
    int k0x = min(max((int)kfx, 0), KK - 1);
    int k0y = min(max((int)kfy, 0), KK - 1);
    int k1x = min(k0x + 1, KK - 1), k1y = min(k0y + 1, KK - 1);
    a00 = k0x * KK + k0y; a01 = k0x * KK + k1y;
    a10 = k1x * KK + k0y; a11 = k1x * KK + k1y;
}

// ---- sort A: LDS-histogram coarse binning; packed {id | lowkey<<20} runs ----
__global__ void coarse_bin(const int* __restrict__ ei0, const int* __restrict__ ei1,
                           int* __restrict__ gcur, int* __restrict__ pk) {
    __shared__ int hist[NCOARSE];
    __shared__ int gbase[NCOARSE];
    int t = threadIdx.x;               // 512 threads
    for (int i = t; i < NCOARSE; i += 512) hist[i] = 0;
    __syncthreads();
    int e0b = blockIdx.x * 4096;
    int ids[8], keys[8], rnk[8];
#pragma unroll
    for (int j = 0; j < 8; j++) {
        int e = e0b + t + j * 512;
        int gk = -1, id = 0;
        if (e < E0) { gk = ei0[E0 + e]; id = e; }
        else if (e < E0 + E1) { int el = e - E0; gk = N0 + ei1[E1 + el]; id = el; }
        ids[j] = id; keys[j] = gk;
    }
#pragma unroll
    for (int j = 0; j < 8; j++)
        if (keys[j] >= 0) rnk[j] = atomicAdd(&hist[keys[j] >> 8], 1);  // native ds_add
    __syncthreads();
    for (int i = t; i < NCOARSE; i += 512)
        gbase[i] = hist[i] ? atomicAdd(&gcur[i], hist[i]) : 0;
    __syncthreads();
#pragma unroll
    for (int j = 0; j < 8; j++) {
        if (keys[j] >= 0) {
            int b = keys[j] >> 8;
            int p = gbase[b] + rnk[j];
            if (p < CAPB) pk[b * CAPB + p] = ids[j] | ((keys[j] & 255) << 20);
        }
    }
}

// ---- sort B: scan 383 bucket counts -> dense bases ----
__global__ void tiny_scan(const int* __restrict__ gcur, int* __restrict__ db,
                          int* __restrict__ off) {
    __shared__ int tmp[NCOARSE];
    int t = threadIdx.x;   // 512
    if (t < NCOARSE) tmp[t] = min(gcur[t], CAPB);
    __syncthreads();
    if (t == 0) {
        int s = 0;
        for (int i = 0; i < NCOARSE; i++) { int c = tmp[i]; tmp[i] = s; s += c; }
    }
    __syncthreads();
    if (t < NCOARSE) db[t] = tmp[t];
    if (t == 0) off[NKEYS] = E0 + E1;
}

// ---- sort C: per-bucket LDS counting sort -> dense idxx + off ----
__global__ void fine_sort(const int* __restrict__ pk, const int* __restrict__ gcur,
                          const int* __restrict__ db,
                          int* __restrict__ idxx, int* __restrict__ off) {
    __shared__ int ent[CAPB];      // 9.6 KB
    __shared__ int rnk[CAPB];      // 9.6 KB
    __shared__ int h2[256];
    __shared__ int sc[256];
    int b = blockIdx.x, t = threadIdx.x;   // 256 threads
    int cb = min(gcur[b], CAPB);
    int base = db[b];
    h2[t] = 0;
    __syncthreads();
    for (int i = t; i < cb; i += 256) {
        int v = pk[b * CAPB + i];
        ent[i] = v;
        rnk[i] = atomicAdd(&h2[(v >> 20) & 255], 1);   // native ds_add
    }
    __syncthreads();
    int v0 = h2[t];
    sc[t] = v0;
    __syncthreads();
    for (int d = 1; d < 256; d <<= 1) {
        int add = (t >= d) ? sc[t - d] : 0;
        __syncthreads();
        sc[t] += add;
        __syncthreads();
    }
    int excl = sc[t] - v0;
    __syncthreads();
    sc[t] = excl;
    __syncthreads();
    int n = (b << 8) + t;
    if (n < NKEYS) off[n] = base + excl;
    for (int i = t; i < cb; i += 256) {
        int v = ent[i];
        idxx[base + sc[(v >> 20) & 255] + rnk[i]] = v & 0xFFFFF;
    }
}

// ---- conv1 fused: 64 nodes/block, 4 threads/node quadrant slices. ----
__global__ __launch_bounds__(256, 5)
void conv1_fused(const int* __restrict__ idxx, const int* __restrict__ off,
                 const float* __restrict__ x, const int* __restrict__ ei0,
                 const float* __restrict__ ps0, const float* __restrict__ W1,
                 const float* __restrict__ root, const float* __restrict__ bias,
                 float* __restrict__ h1) {
    __shared__ float S4[256 * 25];    // 25.6 KB, thread-private slices
    __shared__ float Sr[64 * 25];     // 6.4 KB reduced
    int t = threadIdx.x;
    int nb = blockIdx.x * 64;
    int q = t & 3, nl = t >> 2;
    int n = nb + nl;
    float* sp = S4 + t * 25;
#pragma unroll
    for (int a = 0; a < 25; a++) sp[a] = 0.f;
    int e0 = off[n], e1 = off[n + 1];
    for (int p = e0 + q; p < e1; p += 4) {
        int e = idxx[p];
        int src = ei0[e];
        int a00, a01, a10, a11; float fx, fy;
        taps4(ps0[2 * e] * (KK - 1), ps0[2 * e + 1] * (KK - 1),
              a00, a01, a10, a11, fx, fy);
        float xv = x[src];
        float gx = 1.f - fx, gy = 1.f - fy;
        sp[a00] += gx * gy * xv; sp[a01] += gx * fy * xv;
        sp[a10] += fx * gy * xv; sp[a11] += fx * fy * xv;
    }
    __syncthreads();
    for (int idx2 = t; idx2 < 64 * 25; idx2 += 256) {
        int n2 = idx2 / 25, a = idx2 - n2 * 25;
        Sr[idx2] = S4[(n2 * 4 + 0) * 25 + a] + S4[(n2 * 4 + 1) * 25 + a] +
                   S4[(n2 * 4 + 2) * 25 + a] + S4[(n2 * 4 + 3) * 25 + a];
    }
    __syncthreads();
    int o = t & 31, ng = t >> 5;
    float w1c[25];
#pragma unroll
    for (int a = 0; a < 25; a++) w1c[a] = W1[a * C1 + o];
    float ro = root[o], bo = bias[o];
    for (int j = 0; j < 8; j++) {
        int nl2 = ng * 8 + j;
        int n2 = nb + nl2;
        float acc = 0.f;
#pragma unroll
        for (int a = 0; a < 25; a++) acc += Sr[nl2 * 25 + a] * w1c[a];
        float invd = 1.f / fmaxf((float)(off[n2 + 1] - off[n2]), 1.f);
        float v = acc * invd + x[n2] * ro + bo;
        h1[n2 * C1 + o] = v > 0.f ? v : expm1f(v);
    }
}

// ---- pool1: [100,28,28,32] -> [100,14,14,32] ----
__global__ void pool1(const float* __restrict__ h1, float* __restrict__ p1) {
    int idx = blockIdx.x * blockDim.x + threadIdx.x;
    if (idx >= N1 * C1) return;
    int o = idx & 31; int t = idx >> 5;
    int c = t % 14; int r = (t / 14) % 14; int b = t / 196;
    const float* base = h1 + (((b * 28 + 2 * r) * 28 + 2 * c) * C1 + o);
    float m = fmaxf(fmaxf(base[0], base[C1]),
                    fmaxf(base[28 * C1], base[28 * C1 + C1]));
    p1[idx] = m;
}

// ---- w2t prep: bf16 transposed W2ext [64 o][832 k]; k<800 -> W2, else root2 ----
__global__ void w2t_prep(const float* __restrict__ W2, const float* __restrict__ root2,
                         unsigned short* __restrict__ w2t) {
    int idx = blockIdx.x * blockDim.x + threadIdx.x;
    if (idx >= 64 * KEXT) return;
    int o = idx / KEXT, k = idx - o * KEXT;
    float v = (k < 800) ? W2[k * 64 + o] : root2[(k - 800) * 64 + o];
    w2t[idx] = f2bf(v);
}

// ---- wt1 prep: fc1w [3136,512] fp32 -> transposed bf16 wt1[512][3136] ----
__global__ void wt1_prep(const float* __restrict__ w, unsigned short* __restrict__ wt1) {
    __shared__ unsigned short tile[64 * 66];
    int t = threadIdx.x;
    int k0 = blockIdx.x * 64, j0 = blockIdx.y * 64;
    int jj = t & 63, ks = t >> 6;
    for (int kk = ks; kk < 64; kk += 4)
        tile[kk * 66 + jj] = f2bf(w[(k0 + kk) * FC1_OUT + j0 + jj]);
    __syncthreads();
    int kk = t & 63, js = t >> 6;
    for (int j2 = js; j2 < 64; j2 += 4)
        wt1[(j0 + j2) * FC1_IN + k0 + kk] = tile[kk * 66 + j2];
}

// ---- conv2 fused (MFMA): 8 nodes/block, 5 blocks/CU.
//  Phase0: cooperative staging; Phase1: group-private row RMW (no atomics);
//  Phase1.5: ONE block-level fp32->bf16 conversion pass (invd folded),
//            bf16 buffer aliased over Ul via reg-stage + barriers;
//  Phase2: MFMA with direct b128 bf16 A-frag reads. ----
__global__ __launch_bounds__(256, 5)
void conv2_fused(const float* __restrict__ p1, const int* __restrict__ idxx,
                 const int* __restrict__ off, const int* __restrict__ ei1,
                 const float* __restrict__ ps1,
                 const unsigned short* __restrict__ w2t,
                 const float* __restrict__ b2, float* __restrict__ h2) {
    __shared__ float Ul[8 * ULS];           // 26.8 KB (bf16 view aliases this)
    __shared__ int   es[CH2];
    __shared__ int   et[CH2];
    __shared__ float efx[CH2], efy[CH2];
    unsigned short* Ub = (unsigned short*)Ul;   // 8*856 ushorts = 13.7 KB, fits
    int t = threadIdx.x;
    int nb = blockIdx.x * 8;
    int i = t & 31, g = t >> 5;             // channel lane, group = node 0..7
    float* up = Ul + g * ULS;
#pragma unroll
    for (int a = 0; a < 25; a++) up[a * 32 + i] = 0.f;
    up[800 + i] = p1[(nb + g) * C1 + i];
    int e0 = off[N0 + nb], e1 = off[N0 + nb + 8];
    int my0 = off[N0 + nb + g], my1 = off[N0 + nb + g + 1];
    for (int base = e0; base < e1; base += CH2) {
        int nE = min(e1 - base, CH2);
        __syncthreads();
        for (int j = t; j < nE; j += 256) {
            int e = idxx[base + j];
            es[j] = ei1[e];
            int a00, a01, a10, a11; float fx, fy;
            taps4(ps1[2 * e] * (KK - 1), ps1[2 * e + 1] * (KK - 1),
                  a00, a01, a10, a11, fx, fy);
            et[j] = a00 | (a01 << 5) | (a10 << 10) | (a11 << 15);
            efx[j] = fx; efy[j] = fy;
        }
        __syncthreads();
        int r0 = max(my0 - base, 0);
        int r1 = min(my1 - base, nE);
#pragma unroll 2
        for (int j = r0; j < r1; j++) {
            int src = es[j]; int m = et[j];
            float fx = efx[j], fy = efy[j];
            float xv = p1[src * C1 + i];    // coalesced 128B per group
            float gx = 1.f - fx, gy = 1.f - fy;
            up[(m & 31) * 32 + i]         += gx * gy * xv;
            up[((m >> 5) & 31) * 32 + i]  += gx * fy * xv;
            up[((m >> 10) & 31) * 32 + i] += fx * gy * xv;
            up[((m >> 15) & 31) * 32 + i] += fx * fy * xv;
        }
    }
    __syncthreads();
    // phase 1.5: convert the 8x832 fp32 tile to bf16 once (invd folded).
    // thread (g2 = t>>5, i2 = t&31) owns k = i2*26 .. +25 of node g2's row.
    {
        int g2 = t >> 5, ks = (t & 31) * 26;
        int dgc = off[N0 + nb + g2 + 1] - off[N0 + nb + g2];
        float invd = 1.f / fmaxf((float)dgc, 1.f);
        const float* srcp = Ul + g2 * ULS + ks;
        float rv[26];
#pragma unroll
        for (int j = 0; j < 26; j++) {
            float v = srcp[j];
            rv[j] = (ks + j < 800) ? v * invd : v;
        }
        __syncthreads();                    // all reads done before aliased writes
        unsigned* dstp = (unsigned*)(Ub + g2 * UBS + ks);   // ks even -> dword aligned
#pragma unroll
        for (int j = 0; j < 13; j++) {
            unsigned lo = f2bf(rv[2 * j]), hi = f2bf(rv[2 * j + 1]);
            dstp[j] = lo | (hi << 16);
        }
    }
    __syncthreads();
    // phase 2: MFMA. wave wv -> o-tile. D[node=quad*4+r][o=lane&15]
    int wv = t >> 6, lane = t & 63, quad = lane >> 4, lrow = lane & 15;
    f32x4 acc = {0.f, 0.f, 0.f, 0.f};
    int nodeA = lrow & 7;                   // A rows 8-15 alias 0-7
    const unsigned short* bbase = w2t + (wv * 16 + lrow) * KEXT;
    const unsigned short* abase = Ub + nodeA * UBS;
#pragma unroll
    for (int kc = 0; kc < 26; kc++) {
        bf16x8 a = *(const bf16x8*)(abase + kc * 32 + quad * 8);
        bf16x8 b = *(const bf16x8*)(bbase + kc * 32 + quad * 8);
        acc = __builtin_amdgcn_mfma_f32_16x16x32_bf16(a, b, acc, 0, 0, 0);
    }
    if (quad < 2) {                         // nodes 0..7 only
        int o = wv * 16 + lrow;
        float bo = b2[o];
#pragma unroll
        for (int r = 0; r < 4; r++) {
            int node = quad * 4 + r;
            float v = acc[r] + bo;
            v = v > 0.f ? v : expm1f(v);
            h2[(nb + node) * C2 + o] = v;
        }
    }
}

// ---- pool2 -> bf16 [112 x 3136], rows 100..111 zeroed (M-pad for MFMA) ----
__global__ void pool2b(const float* __restrict__ h2, unsigned short* __restrict__ p2b) {
    int idx = blockIdx.x * blockDim.x + threadIdx.x;
    if (idx >= 112 * FC1_IN) return;
    if (idx >= 100 * FC1_IN) { p2b[idx] = 0; return; }
    int o = idx & 63; int t2 = idx >> 6;
    int c = t2 % 14; int r = (t2 / 14) % 14; int b = t2 / 196;
    const float* base = h2 + (((b * 28 + 2 * r) * 28 + 2 * c) * C2 + o);
    float m = fmaxf(fmaxf(base[0], base[C2]),
                    fmaxf(base[28 * C2], base[28 * C2 + C2]));
    p2b[idx] = f2bf(m);
}

// ---- fc1 MFMA: [112,3136]bf16 @ wt1^T -> z1p fp32 partials (2 kz). ----
__global__ void gemm_fc1(const unsigned short* __restrict__ p2b,
                         const unsigned short* __restrict__ wt1,
                         float* __restrict__ z1p) {
    constexpr int AS = 232;              // 224 + 8 pad, 16B aligned
    __shared__ unsigned short as_[16 * AS];   // 7.4 KB
    int t = threadIdx.x;
    int jt = blockIdx.x, mt = blockIdx.y, kz = blockIdx.z;
    int wv = t >> 6, lane = t & 63, quad = lane >> 4, lrow = lane & 15;
    int m0 = mt * 16;
    int kbase = kz * 1568;
    const unsigned short* bbase = wt1 + (jt * 64 + wv * 16 + lrow) * FC1_IN + kbase;
    f32x4 acc = {0.f, 0.f, 0.f, 0.f};
    for (int ch = 0; ch < 7; ch++) {
        __syncthreads();
        for (int slot = t; slot < 448; slot += 256) {   // 16 rows x 28 uint4
            int r = slot / 28, c = slot - (slot / 28) * 28;
            *(uint4*)(as_ + r * AS + c * 8) =
                *(const uint4*)(p2b + (m0 + r) * FC1_IN + kbase + ch * 224 + c * 8);
        }
        __syncthreads();
        const unsigned short* ab = as_ + lrow * AS;
        const unsigned short* bb = bbase + ch * 224;
#pragma unroll
        for (int kk = 0; kk < 7; kk++) {
            bf16x8 a = *(const bf16x8*)(ab + kk * 32 + quad * 8);
            bf16x8 b = *(const bf16x8*)(bb + kk * 32 + quad * 8);
            acc = __builtin_amdgcn_mfma_f32_16x16x32_bf16(a, b, acc, 0, 0, 0);
        }
    }
    int n = jt * 64 + wv * 16 + lrow;
#pragma unroll
    for (int r = 0; r < 4; r++) {
        int m = m0 + quad * 4 + r;
        z1p[kz * (112 * FC1_OUT) + m * FC1_OUT + n] = acc[r];
    }
}

// ---- fc2 + log_softmax fused; sums 2 fc1 partials, applies fc1 bias+ELU ----
__global__ void fc2_lsm(const float* __restrict__ z1p, const float* __restrict__ fc1b,
                        const float* __restrict__ w, const float* __restrict__ fc2b,
                        float* __restrict__ out) {
    int b = blockIdx.x;
    int t = threadIdx.x;
    int wv = t >> 6;
    int lane = t & 63;
    float acc = 0.f;
#pragma unroll
    for (int m = 0; m < 8; m++) {
        int k = lane * 8 + m;
        float xv = fc1b[k] + z1p[b * FC1_OUT + k] + z1p[112 * FC1_OUT + b * FC1_OUT + k];
        xv = xv > 0.f ? xv : expm1f(xv);
        acc += xv * w[k * 10 + wv];
    }
#pragma unroll
    for (int off = 32; off > 0; off >>= 1) acc += __shfl_down(acc, off);
    __shared__ float zs[10];
    if (lane == 0) {
        float z = acc + fc2b[wv];
        zs[wv] = z > 0.f ? z : expm1f(z);
    }
    __syncthreads();
    if (t < 10) {
        float m = -1e30f;
        for (int jj = 0; jj < 10; jj++) m = fmaxf(m, zs[jj]);
        float s = 0.f;
        for (int jj = 0; jj < 10; jj++) s += expf(zs[jj] - m);
        out[b * 10 + t] = zs[t] - m - logf(s);
    }
}

extern "C" void kernel_launch(void* const* d_in, const int* in_sizes, int n_in,
                              void* d_out, int out_size, void* d_ws, size_t ws_size,
                              hipStream_t stream) {
    const float* x     = (const float*)d_in[0];
    const float* ps0   = (const float*)d_in[1];
    const float* ps1   = (const float*)d_in[2];
    const float* W1    = (const float*)d_in[3];
    const float* root1 = (const float*)d_in[4];
    const float* b1    = (const float*)d_in[5];
    const float* W2    = (const float*)d_in[6];
    const float* root2 = (const float*)d_in[7];
    const float* b2v   = (const float*)d_in[8];
    const float* fc1w  = (const float*)d_in[9];
    const float* fc1b  = (const float*)d_in[10];
    const float* fc2w  = (const float*)d_in[11];
    const float* fc2b  = (const float*)d_in[12];
    const int*   ei0   = (const int*)d_in[13];
    const int*   ei1   = (const int*)d_in[14];

    float* ws = (float*)d_ws;
    int* gcur  = (int*)ws;                         //        383  (memset region)
    int* db    = (int*)(ws + 384);                 //        383
    int* off   = (int*)(ws + 768);                 //     98,001
    int* pk    = (int*)(ws + 98772);               //    919,200 (383 x 2400)
    int* idxx  = (int*)(ws + 1017972);             //    784,000
    float* h1  = ws + 1801972;                     //  2,508,800
    float* p1  = ws + 4310772;                     //    627,200
    float* h2  = ws + 4937972;                     //  1,254,400
    unsigned short* p2b = (unsigned short*)(ws + 6192372);  // 175,616 w
    float* z1p = ws + 6367988;                     //    114,688
    unsigned short* w2t = (unsigned short*)(ws + 6482676);  // 26,624 w
    unsigned short* wt1 = (unsigned short*)(ws + 6509300);  // 802,816 w
    // high water: 7,312,116 words = 29.2 MB

    hipMemsetAsync(gcur, 0, (size_t)NCOARSE * sizeof(int), stream);

    coarse_bin<<<(E0 + E1 + 4095) / 4096, 512, 0, stream>>>(ei0, ei1, gcur, pk);
    tiny_scan<<<1, 512, 0, stream>>>(gcur, db, off);
    fine_sort<<<NCOARSE, 256, 0, stream>>>(pk, gcur, db, idxx, off);
    w2t_prep<<<(64 * KEXT + 255) / 256, 256, 0, stream>>>(W2, root2, w2t);
    wt1_prep<<<dim3(49, 8), 256, 0, stream>>>(fc1w, wt1);
    conv1_fused<<<N0 / 64, 256, 0, stream>>>(idxx, off, x, ei0, ps0,
                                             W1, root1, b1, h1);
    pool1<<<(N1 * C1 + 255) / 256, 256, 0, stream>>>(h1, p1);
    conv2_fused<<<N1 / 8, 256, 0, stream>>>(p1, idxx, off, ei1, ps1, w2t, b2v, h2);
    pool2b<<<(112 * FC1_IN + 255) / 256, 256, 0, stream>>>(h2, p2b);
    gemm_fc1<<<dim3(8, 7, 2), 256, 0, stream>>>(p2b, wt1, z1p);
    fc2_lsm<<<BSZ, 640, 0, stream>>>(z1p, fc1b, fc2w, fc2b, (float*)d_out);
}